// Round 1
// baseline (1004.969 us; speedup 1.0000x reference)
//
#include <hip/hip_runtime.h>
#include <math.h>

#define BB 2
#define KK 8
#define NPB (1<<20)     // pixels per batch item: T*H*W = 8*256*512
#define NPIX (1<<21)    // total pixels
#define NB 16384        // histogram bins over error in [0,2]
#define HALF_NB_F 8192.0f

#define STEP_T (0.1f/31.0f)
#define STEP_Y (1.6f/799.0f)
#define STEP_X (4.16f/1999.0f)

// ws float-offset layout
#define OFF_ACC 0       // 96: (b*8+k)*6 + {count, s_sig, s_sig2, s_t, s_y, s_x}
#define OFF_SEEDBG 96   // 2
#define OFF_SEEDFG 98   // 2
#define OFF_PRM 100     // 96: (b*8+k)*6 + {ct, cy, cx, s_exp, var_k, present}
#define OFF_INSTK 200   // 16
#define OFF_HIST_F 256  // uint32 hist: [(b*8+k)*NB + bin]*2 + label

// ---------------- pass 1: per-(b,k) sums ----------------
__global__ __launch_bounds__(256) void k_acc(const float* __restrict__ pred,
                                             const int* __restrict__ inst,
                                             float* __restrict__ ws) {
  __shared__ float s[49];
  int tid = threadIdx.x;
  if (tid < 49) s[tid] = 0.f;
  __syncthreads();
  int p = blockIdx.x * 256 + tid;
  int b = p >> 20;
  int r = p & (NPB - 1);
  int t = r >> 17, h = (r >> 9) & 255, w = r & 511;
  const float* pb = pred + ((size_t)b * 5 << 20);
  float sig  = pb[(3 << 20) + r];
  float seed = 1.f / (1.f + expf(-pb[(4 << 20) + r]));
  int id = inst[p];
  if (id > 0) {
    int k = id - 1;
    atomicAdd(&s[k*6+0], 1.f);
    atomicAdd(&s[k*6+1], sig);
    atomicAdd(&s[k*6+2], sig * sig);
    atomicAdd(&s[k*6+3], t * STEP_T);
    atomicAdd(&s[k*6+4], h * STEP_Y);
    atomicAdd(&s[k*6+5], w * STEP_X);
  } else {
    atomicAdd(&s[48], seed * seed);
  }
  __syncthreads();
  if (tid < 48) atomicAdd(&ws[OFF_ACC + b*48 + tid], s[tid]);
  if (tid == 48) atomicAdd(&ws[OFF_SEEDBG + b], s[48]);
}

// ---------------- pass 2: derive per-(b,k) params ----------------
__global__ void k_params(float* __restrict__ ws) {
  int i = threadIdx.x;
  if (i < 16) {
    float cnt  = ws[OFF_ACC + i*6 + 0];
    float safe = fmaxf(cnt, 1.f);
    float smean = ws[OFF_ACC + i*6 + 1] / safe;
    float sig2  = ws[OFF_ACC + i*6 + 2] / safe;
    ws[OFF_PRM + i*6 + 0] = ws[OFF_ACC + i*6 + 3] / safe;
    ws[OFF_PRM + i*6 + 1] = ws[OFF_ACC + i*6 + 4] / safe;
    ws[OFF_PRM + i*6 + 2] = ws[OFF_ACC + i*6 + 5] / safe;
    ws[OFF_PRM + i*6 + 3] = expf(10.f * smean);
    ws[OFF_PRM + i*6 + 4] = sig2 - smean * smean;   // var_k (fwd: sg == mean)
    ws[OFF_PRM + i*6 + 5] = (cnt > 0.f) ? 1.f : 0.f;
  }
}

// ---------------- pass 3: error histogram + seed_fg ----------------
__global__ __launch_bounds__(256) void k_hist(const float* __restrict__ pred,
                                              const int* __restrict__ inst,
                                              float* __restrict__ ws) {
  __shared__ float P[KK][5];          // ct, cy, cx, sexp, present
  __shared__ unsigned int hot[KK][4]; // [k][{bin0&neg, bin0&pos, top&neg, top&pos}]
  __shared__ float sfgacc;
  int tid = threadIdx.x;
  int p = blockIdx.x * 256 + tid;
  int b = p >> 20;                    // block is entirely within one b
  if (tid < KK * 5) {
    int k = tid / 5, q = tid % 5;
    P[k][q] = ws[OFF_PRM + (b*8 + k)*6 + (q == 4 ? 5 : q)];
  }
  if (tid < KK * 4) ((unsigned int*)hot)[tid] = 0u;
  if (tid == 0) sfgacc = 0.f;
  __syncthreads();
  int r = p & (NPB - 1);
  int t = r >> 17, h = (r >> 9) & 255, w = r & 511;
  const float* pb = pred + ((size_t)b * 5 << 20);
  float e0 = tanhf(pb[r])             + t * STEP_T;
  float e1 = tanhf(pb[(1 << 20) + r]) + h * STEP_Y;
  float e2 = tanhf(pb[(2 << 20) + r]) + w * STEP_X;
  float seed = 1.f / (1.f + expf(-pb[(4 << 20) + r]));
  int id = inst[p];
  unsigned int* hist = (unsigned int*)(ws + OFF_HIST_F) + (size_t)b * (KK * NB * 2);
  float sfg = 0.f;
  int lane = tid & 63;
  #pragma unroll
  for (int k = 0; k < KK; ++k) {
    if (P[k][4] == 0.f) continue;     // block-uniform branch
    float dt = e0 - P[k][0];
    float dy = e1 - P[k][1];
    float dx = e2 - P[k][2];
    float sq = dt*dt + dy*dy + dx*dx;
    float d = expf(-P[k][3] * sq);
    bool lab = (id == k + 1);
    if (lab) sfg = (seed - d) * (seed - d);   // exactly one k matches
    float e = lab ? (2.f - 2.f*d) : (2.f*d);
    int bin = (int)(e * HALF_NB_F);
    if (bin > NB - 1) bin = NB - 1;
    bool isLow = (bin == 0), isTop = (bin == NB - 1);
    unsigned long long m0 = __ballot(isLow && !lab);
    unsigned long long m1 = __ballot(isLow &&  lab);
    unsigned long long m2 = __ballot(isTop && !lab);
    unsigned long long m3 = __ballot(isTop &&  lab);
    if (lane == 0) {
      if (m0) atomicAdd(&hot[k][0], (unsigned)__popcll(m0));
      if (m1) atomicAdd(&hot[k][1], (unsigned)__popcll(m1));
      if (m2) atomicAdd(&hot[k][2], (unsigned)__popcll(m2));
      if (m3) atomicAdd(&hot[k][3], (unsigned)__popcll(m3));
    }
    if (!isLow && !isTop)
      atomicAdd(&hist[(k*NB + bin)*2 + (lab ? 1 : 0)], 1u);
  }
  if (id > 0) atomicAdd(&sfgacc, sfg);
  __syncthreads();
  if (tid < KK * 4) {
    int k = tid >> 2, j = tid & 3;
    unsigned int v = hot[k][j];
    if (v) atomicAdd(&hist[(k*NB + ((j >= 2) ? (NB - 1) : 0))*2 + (j & 1)], v);
  }
  if (tid == 0) atomicAdd(&ws[OFF_SEEDFG + b], sfgacc);
}

// ---------------- pass 4: Lovasz hinge per segment from histogram ----------------
__global__ __launch_bounds__(256) void k_lovasz(float* __restrict__ ws) {
  int seg = blockIdx.x;               // b*8+k
  int tid = threadIdx.x;
  float pres = ws[OFF_PRM + seg*6 + 5];
  if (pres == 0.f) { if (tid == 0) ws[OFF_INSTK + seg] = 0.f; return; }
  double gts = (double)ws[OFF_ACC + seg*6 + 0];
  const unsigned int* hist = (const unsigned int*)(ws + OFF_HIST_F) + (size_t)seg * (NB * 2);
  __shared__ unsigned int sp[256], sn[256];
  __shared__ double red[256];
  unsigned int carry_p = 0, carry_n = 0;
  double sum = 0.0;
  for (int chunk = 0; chunk < NB / 256; ++chunk) {
    int pos = chunk * 256 + tid;      // position in DESCENDING error order
    int bin = NB - 1 - pos;
    unsigned int pp = hist[bin*2 + 1];
    unsigned int nn = hist[bin*2 + 0];
    sp[tid] = pp; sn[tid] = nn;
    __syncthreads();
    for (int off = 1; off < 256; off <<= 1) {   // Hillis-Steele inclusive scan
      unsigned int tp = 0, tn = 0;
      if (tid >= off) { tp = sp[tid - off]; tn = sn[tid - off]; }
      __syncthreads();
      sp[tid] += tp; sn[tid] += tn;
      __syncthreads();
    }
    unsigned int ip = carry_p + sp[tid];
    unsigned int in_ = carry_n + sn[tid];
    if (pp + nn) {
      double ep = (double)(ip - pp), en = (double)(in_ - nn);
      double js = 1.0 - (gts - ep) / (gts + en);            // jac before run (0 at start)
      double je = 1.0 - (gts - (double)ip) / (gts + (double)in_); // jac after run
      double eh = ((double)bin + 0.5) * (2.0 / NB);
      sum += eh * (je - js);
    }
    unsigned int totp = sp[255], totn = sn[255];
    __syncthreads();
    carry_p += totp; carry_n += totn;
  }
  red[tid] = sum;
  __syncthreads();
  for (int off = 128; off > 0; off >>= 1) {
    if (tid < off) red[tid] += red[tid + off];
    __syncthreads();
  }
  if (tid == 0) ws[OFF_INSTK + seg] = (float)red[0];
}

// ---------------- pass 5: combine ----------------
__global__ void k_final(const float* __restrict__ ws, float* __restrict__ out) {
  if (threadIdx.x == 0 && blockIdx.x == 0) {
    double tot = 0.0;
    for (int b = 0; b < BB; ++b) {
      double il = 0.0, vl = 0.0, ob = 0.0;
      for (int k = 0; k < KK; ++k) {
        int seg = b*8 + k;
        double pres = ws[OFF_PRM + seg*6 + 5];
        il += (double)ws[OFF_INSTK + seg] * pres;
        vl += (double)ws[OFF_PRM + seg*6 + 4] * pres;
        ob += pres;
      }
      double so = (ob > 1.0) ? ob : 1.0;
      double sl = ((double)ws[OFF_SEEDBG + b] + (double)ws[OFF_SEEDFG + b]) / (256.0 * 512.0);
      tot += il / so + 10.0 * vl / so + sl;
    }
    out[0] = (float)(tot / BB);
  }
}

extern "C" void kernel_launch(void* const* d_in, const int* in_sizes, int n_in,
                              void* d_out, int out_size, void* d_ws, size_t ws_size,
                              hipStream_t stream) {
  const float* pred = (const float*)d_in[0];
  const int* inst = (const int*)d_in[1];
  float* ws = (float*)d_ws;
  float* out = (float*)d_out;
  size_t zero_bytes = 1024 + (size_t)BB * KK * NB * 2 * sizeof(unsigned int);
  hipMemsetAsync(d_ws, 0, zero_bytes, stream);
  k_acc<<<NPIX / 256, 256, 0, stream>>>(pred, inst, ws);
  k_params<<<1, 64, 0, stream>>>(ws);
  k_hist<<<NPIX / 256, 256, 0, stream>>>(pred, inst, ws);
  k_lovasz<<<16, 256, 0, stream>>>(ws);
  k_final<<<1, 64, 0, stream>>>(ws, out);
}

// Round 2
// 240.134 us; speedup vs baseline: 4.1850x; 4.1850x over previous
//
#include <hip/hip_runtime.h>
#include <math.h>

#define BB 2
#define KK 8
#define NPB (1<<20)     // pixels per batch item: T*H*W = 8*256*512
#define NPIX (1<<21)    // total pixels
#define NB 2048         // histogram bins over error in [0,2]
#define HALF_NB_F 1024.0f
#define PXB 4096        // pixels per block (k_acc / k_hist)
#define ITERS (PXB/256) // 16

#define STEP_T (0.1f/31.0f)
#define STEP_Y (1.6f/799.0f)
#define STEP_X (4.16f/1999.0f)

// ws float-offset layout
#define OFF_ACC 0       // 96: (b*8+k)*6 + {count, s_sig, s_sig2, s_t, s_y, s_x}
#define OFF_SEEDBG 96   // 2
#define OFF_SEEDFG 98   // 2
#define OFF_PRM 100     // 96: (b*8+k)*6 + {ct, cy, cx, s_exp, var_k, present}
#define OFF_INSTK 200   // 16
#define OFF_HIST_F 256  // uint32 hist: [((b*8+k)*NB + bin)*2 + label]

// ---------------- pass 1: per-(b,k) sums (conflict-free LDS columns) ----------------
__global__ __launch_bounds__(256) void k_acc(const float* __restrict__ pred,
                                             const int* __restrict__ inst,
                                             float* __restrict__ ws) {
  __shared__ float s[48 * 256];
  int tid = threadIdx.x;
  for (int f = 0; f < 48; ++f) s[f * 256 + tid] = 0.f;
  __syncthreads();
  int blk = blockIdx.x;
  int b = blk >> 8;
  int rbase = (blk & 255) * PXB;
  const float* sig_p = pred + ((size_t)b * 5 << 20) + (3 << 20);
  const int* ip = inst + ((size_t)b << 20);
  for (int it = 0; it < ITERS; ++it) {
    int r = rbase + it * 256 + tid;
    float sg = sig_p[r];
    int id = ip[r];
    if (id > 0) {
      int base = (id - 1) * 6 * 256 + tid;
      int t = r >> 17, h = (r >> 9) & 255, w = r & 511;
      s[base]        += 1.f;
      s[base + 256]  += sg;
      s[base + 512]  += sg * sg;
      s[base + 768]  += (float)t;
      s[base + 1024] += (float)h;
      s[base + 1280] += (float)w;
    }
  }
  // tree-reduce 256 columns -> column 0, all 48 fields
  for (int lev = 7; lev >= 0; --lev) {
    int off = 1 << lev;
    __syncthreads();
    for (int idx = tid; idx < 48 * off; idx += 256) {
      int f = idx >> lev, c = idx & (off - 1);
      s[f * 256 + c] += s[f * 256 + c + off];
    }
  }
  __syncthreads();
  if (tid < 48) {
    float v = s[tid * 256];
    int j = tid % 6;
    if (j == 3) v *= STEP_T;
    else if (j == 4) v *= STEP_Y;
    else if (j == 5) v *= STEP_X;
    atomicAdd(&ws[OFF_ACC + b * 48 + tid], v);
  }
}

// ---------------- pass 2: derive per-(b,k) params ----------------
__global__ void k_params(float* __restrict__ ws) {
  int i = threadIdx.x;
  if (i < 16) {
    float cnt  = ws[OFF_ACC + i*6 + 0];
    float safe = fmaxf(cnt, 1.f);
    float smean = ws[OFF_ACC + i*6 + 1] / safe;
    float sig2  = ws[OFF_ACC + i*6 + 2] / safe;
    ws[OFF_PRM + i*6 + 0] = ws[OFF_ACC + i*6 + 3] / safe;
    ws[OFF_PRM + i*6 + 1] = ws[OFF_ACC + i*6 + 4] / safe;
    ws[OFF_PRM + i*6 + 2] = ws[OFF_ACC + i*6 + 5] / safe;
    ws[OFF_PRM + i*6 + 3] = expf(10.f * smean);
    ws[OFF_PRM + i*6 + 4] = sig2 - smean * smean;   // var_k (fwd: sg == mean)
    ws[OFF_PRM + i*6 + 5] = (cnt > 0.f) ? 1.f : 0.f;
  }
}

__device__ __forceinline__ float fast_tanh(float x) {
  x = fminf(fmaxf(x, -15.f), 15.f);
  float ex = __expf(2.f * x);
  return (ex - 1.f) / (ex + 1.f);
}

// ---------------- pass 3: LDS-private histogram + seed losses ----------------
__global__ __launch_bounds__(256, 2) void k_hist(const float* __restrict__ pred,
                                                 const int* __restrict__ inst,
                                                 float* __restrict__ ws) {
  __shared__ unsigned int hist[KK * NB];  // packed: neg low16, pos high16
  __shared__ float Ps[KK * 4];
  __shared__ unsigned int pmask_s;
  __shared__ float wred[8];
  int tid = threadIdx.x;
  int blk = blockIdx.x;
  int b = blk >> 8;
  for (int i = tid; i < KK * NB; i += 256) hist[i] = 0u;
  if (tid < KK) {
    int seg = b * 8 + tid;
    Ps[tid*4+0] = ws[OFF_PRM + seg*6 + 0];
    Ps[tid*4+1] = ws[OFF_PRM + seg*6 + 1];
    Ps[tid*4+2] = ws[OFF_PRM + seg*6 + 2];
    Ps[tid*4+3] = ws[OFF_PRM + seg*6 + 3];
  }
  if (tid == 0) {
    unsigned m = 0;
    for (int k = 0; k < KK; ++k)
      if (ws[OFF_PRM + (b*8+k)*6 + 5] > 0.f) m |= 1u << k;
    pmask_s = m;
  }
  __syncthreads();
  float ct[KK], cy[KK], cx[KK], se[KK];
  #pragma unroll
  for (int k = 0; k < KK; ++k) {
    ct[k] = Ps[k*4+0]; cy[k] = Ps[k*4+1]; cx[k] = Ps[k*4+2]; se[k] = Ps[k*4+3];
  }
  unsigned pmask = pmask_s;
  int rbase = (blk & 255) * PXB;
  const float* pb = pred + ((size_t)b * 5 << 20);
  const int* ip = inst + ((size_t)b << 20);
  unsigned int* gh = (unsigned int*)(ws + OFF_HIST_F) + (size_t)b * (KK * NB * 2);
  float sbg = 0.f, sfg = 0.f;
  for (int it = 0; it < ITERS; ++it) {
    int r = rbase + it * 256 + tid;
    int t = r >> 17, h = (r >> 9) & 255, w = r & 511;
    float e0 = fast_tanh(pb[r])             + t * STEP_T;
    float e1 = fast_tanh(pb[(1 << 20) + r]) + h * STEP_Y;
    float e2 = fast_tanh(pb[(2 << 20) + r]) + w * STEP_X;
    float seed = 1.f / (1.f + __expf(-pb[(4 << 20) + r]));
    int id = ip[r];
    if (id == 0) sbg += seed * seed;
    #pragma unroll
    for (int k = 0; k < KK; ++k) {
      if (!((pmask >> k) & 1)) continue;   // wave-uniform
      float dt = e0 - ct[k], dy = e1 - cy[k], dx = e2 - cx[k];
      float d = __expf(-se[k] * (dt*dt + dy*dy + dx*dx));
      bool lab = (id == k + 1);
      if (lab) { float df = seed - d; sfg += df * df; }
      float e = lab ? (2.f - 2.f * d) : (2.f * d);
      int bin = (int)(e * HALF_NB_F);
      bin = min(bin, NB - 1);
      bool isLow = (bin == 0), isTop = (bin == NB - 1);
      unsigned long long m0 = __ballot(isLow && !lab);
      unsigned long long m1 = __ballot(isLow &&  lab);
      unsigned long long m2 = __ballot(isTop && !lab);
      unsigned long long m3 = __ballot(isTop &&  lab);
      if ((tid & 63) == 0) {
        unsigned vlow = (unsigned)__popcll(m0) + ((unsigned)__popcll(m1) << 16);
        unsigned vtop = (unsigned)__popcll(m2) + ((unsigned)__popcll(m3) << 16);
        if (vlow) atomicAdd(&hist[k * NB], vlow);
        if (vtop) atomicAdd(&hist[k * NB + NB - 1], vtop);
      }
      if (!isLow && !isTop)
        atomicAdd(&hist[k * NB + bin], lab ? 0x10000u : 1u);
    }
  }
  // reduce seed accumulators
  for (int off = 32; off; off >>= 1) {
    sbg += __shfl_down(sbg, off);
    sfg += __shfl_down(sfg, off);
  }
  if ((tid & 63) == 0) { wred[(tid >> 6) * 2] = sbg; wred[(tid >> 6) * 2 + 1] = sfg; }
  __syncthreads();
  if (tid == 0) {
    atomicAdd(&ws[OFF_SEEDBG + b], wred[0] + wred[2] + wred[4] + wred[6]);
    atomicAdd(&ws[OFF_SEEDFG + b], wred[1] + wred[3] + wred[5] + wred[7]);
  }
  // flush nonzero words to global
  __syncthreads();
  for (int i = tid; i < KK * NB; i += 256) {
    unsigned v = hist[i];
    if (v) {
      unsigned neg = v & 0xFFFFu, pos = v >> 16;
      unsigned idx = (unsigned)i * 2;     // i = k*NB+bin
      if (neg) atomicAdd(&gh[idx], neg);
      if (pos) atomicAdd(&gh[idx + 1], pos);
    }
  }
}

// ---------------- pass 4: Lovasz hinge per segment from histogram ----------------
__global__ __launch_bounds__(256) void k_lovasz(float* __restrict__ ws) {
  int seg = blockIdx.x;               // b*8+k
  int tid = threadIdx.x;
  float pres = ws[OFF_PRM + seg*6 + 5];
  if (pres == 0.f) { if (tid == 0) ws[OFF_INSTK + seg] = 0.f; return; }
  double gts = (double)ws[OFF_ACC + seg*6 + 0];
  const unsigned int* hist = (const unsigned int*)(ws + OFF_HIST_F) + (size_t)seg * (NB * 2);
  __shared__ unsigned int sp[256], sn[256];
  __shared__ double red[256];
  unsigned int carry_p = 0, carry_n = 0;
  double sum = 0.0;
  for (int chunk = 0; chunk < NB / 256; ++chunk) {
    int pos = chunk * 256 + tid;      // position in DESCENDING error order
    int bin = NB - 1 - pos;
    unsigned int pp = hist[bin*2 + 1];
    unsigned int nn = hist[bin*2 + 0];
    sp[tid] = pp; sn[tid] = nn;
    __syncthreads();
    for (int off = 1; off < 256; off <<= 1) {   // Hillis-Steele inclusive scan
      unsigned int tp = 0, tn = 0;
      if (tid >= off) { tp = sp[tid - off]; tn = sn[tid - off]; }
      __syncthreads();
      sp[tid] += tp; sn[tid] += tn;
      __syncthreads();
    }
    unsigned int ip = carry_p + sp[tid];
    unsigned int in_ = carry_n + sn[tid];
    if (pp + nn) {
      double ep = (double)(ip - pp), en = (double)(in_ - nn);
      double js = 1.0 - (gts - ep) / (gts + en);
      double je = 1.0 - (gts - (double)ip) / (gts + (double)in_);
      double eh = ((double)bin + 0.5) * (2.0 / NB);
      sum += eh * (je - js);
    }
    unsigned int totp = sp[255], totn = sn[255];
    __syncthreads();
    carry_p += totp; carry_n += totn;
  }
  red[tid] = sum;
  __syncthreads();
  for (int off = 128; off > 0; off >>= 1) {
    if (tid < off) red[tid] += red[tid + off];
    __syncthreads();
  }
  if (tid == 0) ws[OFF_INSTK + seg] = (float)red[0];
}

// ---------------- pass 5: combine ----------------
__global__ void k_final(const float* __restrict__ ws, float* __restrict__ out) {
  if (threadIdx.x == 0 && blockIdx.x == 0) {
    double tot = 0.0;
    for (int b = 0; b < BB; ++b) {
      double il = 0.0, vl = 0.0, ob = 0.0;
      for (int k = 0; k < KK; ++k) {
        int seg = b*8 + k;
        double pres = ws[OFF_PRM + seg*6 + 5];
        il += (double)ws[OFF_INSTK + seg] * pres;
        vl += (double)ws[OFF_PRM + seg*6 + 4] * pres;
        ob += pres;
      }
      double so = (ob > 1.0) ? ob : 1.0;
      double sl = ((double)ws[OFF_SEEDBG + b] + (double)ws[OFF_SEEDFG + b]) / (256.0 * 512.0);
      tot += il / so + 10.0 * vl / so + sl;
    }
    out[0] = (float)(tot / BB);
  }
}

extern "C" void kernel_launch(void* const* d_in, const int* in_sizes, int n_in,
                              void* d_out, int out_size, void* d_ws, size_t ws_size,
                              hipStream_t stream) {
  const float* pred = (const float*)d_in[0];
  const int* inst = (const int*)d_in[1];
  float* ws = (float*)d_ws;
  float* out = (float*)d_out;
  size_t zero_bytes = 1024 + (size_t)BB * KK * NB * 2 * sizeof(unsigned int);
  hipMemsetAsync(d_ws, 0, zero_bytes, stream);
  k_acc<<<512, 256, 0, stream>>>(pred, inst, ws);
  k_params<<<1, 64, 0, stream>>>(ws);
  k_hist<<<512, 256, 0, stream>>>(pred, inst, ws);
  k_lovasz<<<16, 256, 0, stream>>>(ws);
  k_final<<<1, 64, 0, stream>>>(ws, out);
}

// Round 3
// 208.492 us; speedup vs baseline: 4.8202x; 1.1518x over previous
//
#include <hip/hip_runtime.h>
#include <math.h>

#define BB 2
#define KK 8
#define NPB (1<<20)       // pixels per batch item: T*H*W
#define NB 1024           // histogram bins over error in [0,2]
#define HALF_NB_F 512.0f
#define NCOPY 8

#define PXB_H 2048
#define GRID_H (BB*NPB/PXB_H)   // 1024
#define ITERS_H (PXB_H/512)     // 4 (2 px/thread/iter)
#define PXB_A 4096
#define GRID_A (BB*NPB/PXB_A)   // 512
#define ITERS_A (PXB_A/512)     // 8

#define STEP_T (0.1f/31.0f)
#define STEP_Y (1.6f/799.0f)
#define STEP_X (4.16f/1999.0f)

// ws float-offset layout
#define OFF_ACC 0       // 96: seg*6 + {count, s_sig, s_sig2, s_t, s_y, s_x}
#define OFF_SEEDBG 96
#define OFF_SEEDFG 98
#define OFF_PRM 100     // 96: seg*6 + {ct, cy, cx, s_exp, var_k, present}
#define OFF_INSTK 200   // 16
#define CNT0 240        // uint counter (k_acc last-block)
#define CNT1 241        // uint counter (k_lovasz last-block)
#define OFF_HIST_F 256  // NCOPY * [seg][bin][2] u32

// ---------------- pass 1: per-(b,k) sums + fused params ----------------
__global__ __launch_bounds__(256) void k_acc(const float* __restrict__ pred,
                                             const int* __restrict__ inst,
                                             float* __restrict__ ws) {
  __shared__ float s[48 * 256];
  __shared__ int lastA;
  int tid = threadIdx.x;
  for (int f = 0; f < 48; ++f) s[f * 256 + tid] = 0.f;
  __syncthreads();
  int blk = blockIdx.x;
  int b = blk >> 8;
  int rbase = (blk & 255) * PXB_A;
  const float* sig_p = pred + ((size_t)b * 5 << 20) + (3 << 20);
  const int* ip = inst + ((size_t)b << 20);
  for (int it = 0; it < ITERS_A; ++it) {
    int r = rbase + it * 512 + 2 * tid;
    float2 sg = *(const float2*)(sig_p + r);
    int2 id2 = *(const int2*)(ip + r);
    int t = r >> 17, h = (r >> 9) & 255, w = r & 511;
    if (id2.x > 0) {
      int base = (id2.x - 1) * 1536 + tid;
      s[base]        += 1.f;
      s[base + 256]  += sg.x;
      s[base + 512]  += sg.x * sg.x;
      s[base + 768]  += (float)t;
      s[base + 1024] += (float)h;
      s[base + 1280] += (float)w;
    }
    if (id2.y > 0) {
      int base = (id2.y - 1) * 1536 + tid;
      s[base]        += 1.f;
      s[base + 256]  += sg.y;
      s[base + 512]  += sg.y * sg.y;
      s[base + 768]  += (float)t;
      s[base + 1024] += (float)h;
      s[base + 1280] += (float)(w + 1);
    }
  }
  for (int lev = 7; lev >= 0; --lev) {
    int off = 1 << lev;
    __syncthreads();
    for (int idx = tid; idx < 48 * off; idx += 256) {
      int f = idx >> lev, c = idx & (off - 1);
      s[f * 256 + c] += s[f * 256 + c + off];
    }
  }
  __syncthreads();
  if (tid < 48) {
    float v = s[tid * 256];
    int j = tid % 6;
    if (j == 3) v *= STEP_T;
    else if (j == 4) v *= STEP_Y;
    else if (j == 5) v *= STEP_X;
    atomicAdd(&ws[OFF_ACC + b * 48 + tid], v);
  }
  __syncthreads();   // drains this block's atomics (waitcnt before barrier)
  if (tid == 0) {
    __threadfence();
    lastA = (atomicAdd((unsigned*)ws + CNT0, 1u) == GRID_A - 1) ? 1 : 0;
  }
  __syncthreads();
  if (lastA && tid < 16) {
    __threadfence();
    float cnt = atomicAdd(&ws[OFF_ACC + tid*6 + 0], 0.f);
    float s1  = atomicAdd(&ws[OFF_ACC + tid*6 + 1], 0.f);
    float s2  = atomicAdd(&ws[OFF_ACC + tid*6 + 2], 0.f);
    float st  = atomicAdd(&ws[OFF_ACC + tid*6 + 3], 0.f);
    float sy  = atomicAdd(&ws[OFF_ACC + tid*6 + 4], 0.f);
    float sx  = atomicAdd(&ws[OFF_ACC + tid*6 + 5], 0.f);
    float safe = fmaxf(cnt, 1.f);
    float smean = s1 / safe;
    ws[OFF_PRM + tid*6 + 0] = st / safe;
    ws[OFF_PRM + tid*6 + 1] = sy / safe;
    ws[OFF_PRM + tid*6 + 2] = sx / safe;
    ws[OFF_PRM + tid*6 + 3] = __expf(10.f * smean);
    ws[OFF_PRM + tid*6 + 4] = s2 / safe - smean * smean;
    ws[OFF_PRM + tid*6 + 5] = (cnt > 0.f) ? 1.f : 0.f;
  }
}

__device__ __forceinline__ float fast_tanh(float x) {
  x = fminf(fmaxf(x, -15.f), 15.f);
  float ex = __expf(2.f * x);
  return (ex - 1.f) / (ex + 1.f);
}

// ---------------- pass 2: LDS-private histogram + seed losses ----------------
__global__ __launch_bounds__(256) void k_hist(const float* __restrict__ pred,
                                              const int* __restrict__ inst,
                                              float* __restrict__ ws) {
  __shared__ unsigned int hist[KK * NB];  // packed: neg low16, pos high16
  __shared__ float Ps[KK * 4];
  __shared__ unsigned int pmask_s;
  __shared__ float wred[8];
  int tid = threadIdx.x;
  int blk = blockIdx.x;
  int b = blk >> 9;
  for (int i = tid; i < KK * NB; i += 256) hist[i] = 0u;
  if (tid < KK) {
    int seg = b * 8 + tid;
    Ps[tid*4+0] = ws[OFF_PRM + seg*6 + 0];
    Ps[tid*4+1] = ws[OFF_PRM + seg*6 + 1];
    Ps[tid*4+2] = ws[OFF_PRM + seg*6 + 2];
    Ps[tid*4+3] = ws[OFF_PRM + seg*6 + 3];
  }
  if (tid == 0) {
    unsigned m = 0;
    for (int k = 0; k < KK; ++k)
      if (ws[OFF_PRM + (b*8+k)*6 + 5] > 0.f) m |= 1u << k;
    pmask_s = m;
  }
  __syncthreads();
  float ct[KK], cy[KK], cx[KK], se[KK];
  #pragma unroll
  for (int k = 0; k < KK; ++k) {
    ct[k] = Ps[k*4+0]; cy[k] = Ps[k*4+1]; cx[k] = Ps[k*4+2]; se[k] = Ps[k*4+3];
  }
  unsigned pmask = pmask_s;
  int rbase = (blk & 511) * PXB_H;
  const float* pb = pred + ((size_t)b * 5 << 20);
  const int* ip = inst + ((size_t)b << 20);
  float sbg = 0.f, sfg = 0.f;
  int lane = tid & 63;
  for (int it = 0; it < ITERS_H; ++it) {
    int r = rbase + it * 512 + 2 * tid;
    int t = r >> 17, h = (r >> 9) & 255, w = r & 511;
    float2 p0 = *(const float2*)(pb + r);
    float2 p1 = *(const float2*)(pb + (1 << 20) + r);
    float2 p2 = *(const float2*)(pb + (2 << 20) + r);
    float2 p4 = *(const float2*)(pb + (4 << 20) + r);
    int2 id2 = *(const int2*)(ip + r);
    float e0a = fast_tanh(p0.x) + t * STEP_T;
    float e0b = fast_tanh(p0.y) + t * STEP_T;
    float e1a = fast_tanh(p1.x) + h * STEP_Y;
    float e1b = fast_tanh(p1.y) + h * STEP_Y;
    float e2a = fast_tanh(p2.x) + w * STEP_X;
    float e2b = fast_tanh(p2.y) + (w + 1) * STEP_X;
    float seeda = 1.f / (1.f + __expf(-p4.x));
    float seedb = 1.f / (1.f + __expf(-p4.y));
    if (id2.x == 0) sbg += seeda * seeda;
    if (id2.y == 0) sbg += seedb * seedb;
    #pragma unroll
    for (int k = 0; k < KK; ++k) {
      if (!((pmask >> k) & 1)) continue;   // wave-uniform
      float dta = e0a - ct[k], dya = e1a - cy[k], dxa = e2a - cx[k];
      float dtb = e0b - ct[k], dyb = e1b - cy[k], dxb = e2b - cx[k];
      float da = __expf(-se[k] * (dta*dta + dya*dya + dxa*dxa));
      float db = __expf(-se[k] * (dtb*dtb + dyb*dyb + dxb*dxb));
      bool laba = (id2.x == k + 1), labb = (id2.y == k + 1);
      if (laba) { float df = seeda - da; sfg += df * df; }
      if (labb) { float df = seedb - db; sfg += df * df; }
      float ea = laba ? (2.f - 2.f * da) : (2.f * da);
      float eb = labb ? (2.f - 2.f * db) : (2.f * db);
      int bina = min((int)(ea * HALF_NB_F), NB - 1);
      int binb = min((int)(eb * HALF_NB_F), NB - 1);
      bool lowa = (bina == 0), topa = (bina == NB - 1);
      bool lowb = (binb == 0), topb = (binb == NB - 1);
      unsigned long long mla = __ballot(laba), mlo_a = __ballot(lowa), mto_a = __ballot(topa);
      unsigned long long mlb = __ballot(labb), mlo_b = __ballot(lowb), mto_b = __ballot(topb);
      if (lane == 0) {
        unsigned vlow = (unsigned)__popcll(mlo_a & ~mla) + (unsigned)__popcll(mlo_b & ~mlb)
                      + (((unsigned)__popcll(mlo_a & mla) + (unsigned)__popcll(mlo_b & mlb)) << 16);
        unsigned vtop = (unsigned)__popcll(mto_a & ~mla) + (unsigned)__popcll(mto_b & ~mlb)
                      + (((unsigned)__popcll(mto_a & mla) + (unsigned)__popcll(mto_b & mlb)) << 16);
        if (vlow) atomicAdd(&hist[k * NB], vlow);
        if (vtop) atomicAdd(&hist[k * NB + NB - 1], vtop);
      }
      if (!lowa && !topa) atomicAdd(&hist[k * NB + bina], laba ? 0x10000u : 1u);
      if (!lowb && !topb) atomicAdd(&hist[k * NB + binb], labb ? 0x10000u : 1u);
    }
  }
  for (int off = 32; off; off >>= 1) {
    sbg += __shfl_down(sbg, off);
    sfg += __shfl_down(sfg, off);
  }
  if (lane == 0) { wred[(tid >> 6) * 2] = sbg; wred[(tid >> 6) * 2 + 1] = sfg; }
  __syncthreads();
  if (tid == 0) {
    atomicAdd(&ws[OFF_SEEDBG + b], wred[0] + wred[2] + wred[4] + wred[6]);
    atomicAdd(&ws[OFF_SEEDFG + b], wred[1] + wred[3] + wred[5] + wred[7]);
  }
  // flush nonzero words into this block's histogram copy (blk&7 ~ XCD round-robin)
  __syncthreads();
  unsigned int* gh = (unsigned int*)(ws + OFF_HIST_F);
  size_t cbase = (size_t)(blk & 7) * (16 * NB * 2) + (size_t)b * (8 * NB * 2);
  for (int i = tid; i < KK * NB; i += 256) {
    unsigned v = hist[i];
    if (v) {
      unsigned neg = v & 0xFFFFu, pos = v >> 16;
      size_t idx = cbase + (size_t)i * 2;
      if (neg) atomicAdd(&gh[idx], neg);
      if (pos) atomicAdd(&gh[idx + 1], pos);
    }
  }
}

// ---------------- pass 3: Lovasz per segment (wave scan) + fused final ----------------
__global__ __launch_bounds__(256) void k_lovasz(float* __restrict__ ws, float* __restrict__ out) {
  int seg = blockIdx.x;               // b*8+k
  int tid = threadIdx.x;
  int lane = tid & 63, wv = tid >> 6;
  __shared__ unsigned long long wtot[4];
  __shared__ double dred[4];
  __shared__ int lastL;
  float pres = ws[OFF_PRM + seg*6 + 5];
  double total = 0.0;
  if (pres != 0.f) {
    double gts = (double)ws[OFF_ACC + seg*6 + 0];
    const unsigned int* gh = (const unsigned int*)(ws + OFF_HIST_F);
    unsigned long long carry = 0;
    double sum = 0.0;
    for (int chunk = 0; chunk < NB / 256; ++chunk) {
      int pos = chunk * 256 + tid;    // descending-error position
      int bin = NB - 1 - pos;
      unsigned int nn = 0, pp = 0;
      size_t off0 = (size_t)seg * (NB * 2) + (size_t)bin * 2;
      #pragma unroll
      for (int c = 0; c < NCOPY; ++c) {
        nn += gh[off0];
        pp += gh[off0 + 1];
        off0 += (size_t)16 * NB * 2;
      }
      unsigned long long v = ((unsigned long long)pp << 32) | nn;
      unsigned long long orig = v;
      #pragma unroll
      for (int o = 1; o < 64; o <<= 1) {
        unsigned long long u = (unsigned long long)__shfl_up((long long)v, o, 64);
        if (lane >= o) v += u;
      }
      if (lane == 63) wtot[wv] = v;
      __syncthreads();
      unsigned long long add = carry;
      for (int j = 0; j < wv; ++j) add += wtot[j];
      v += add;
      if (orig) {
        unsigned int ip = (unsigned)(v >> 32), in_ = (unsigned)v;
        unsigned int ppx = (unsigned)(orig >> 32), nnx = (unsigned)orig;
        double ep = (double)(ip - ppx), en = (double)(in_ - nnx);
        double js = 1.0 - (gts - ep) / (gts + en);
        double je = 1.0 - (gts - (double)ip) / (gts + (double)in_);
        sum += ((double)bin + 0.5) * (2.0 / NB) * (je - js);
      }
      unsigned long long ctot = carry + wtot[0] + wtot[1] + wtot[2] + wtot[3];
      __syncthreads();
      carry = ctot;
    }
    for (int o = 32; o; o >>= 1) sum += __shfl_down(sum, o);
    if (lane == 0) dred[wv] = sum;
    __syncthreads();
    if (tid == 0) total = dred[0] + dred[1] + dred[2] + dred[3];
  }
  if (tid == 0) {
    atomicExch(&ws[OFF_INSTK + seg], (float)total);
    __threadfence();
    lastL = (atomicAdd((unsigned*)ws + CNT1, 1u) == 15) ? 1 : 0;
  }
  __syncthreads();
  if (lastL && tid == 0) {
    __threadfence();
    double tot = 0.0;
    for (int bb = 0; bb < BB; ++bb) {
      double il = 0.0, vl = 0.0, ob = 0.0;
      for (int k2 = 0; k2 < KK; ++k2) {
        int s2 = bb * 8 + k2;
        double pr = (double)ws[OFF_PRM + s2*6 + 5];
        il += (double)atomicAdd(&ws[OFF_INSTK + s2], 0.f) * pr;
        vl += (double)ws[OFF_PRM + s2*6 + 4] * pr;
        ob += pr;
      }
      double so = (ob > 1.0) ? ob : 1.0;
      double sl = ((double)ws[OFF_SEEDBG + bb] + (double)ws[OFF_SEEDFG + bb]) / (256.0 * 512.0);
      tot += il / so + 10.0 * vl / so + sl;
    }
    out[0] = (float)(tot / BB);
  }
}

extern "C" void kernel_launch(void* const* d_in, const int* in_sizes, int n_in,
                              void* d_out, int out_size, void* d_ws, size_t ws_size,
                              hipStream_t stream) {
  const float* pred = (const float*)d_in[0];
  const int* inst = (const int*)d_in[1];
  float* ws = (float*)d_ws;
  float* out = (float*)d_out;
  size_t zero_bytes = 1024 + (size_t)NCOPY * 16 * NB * 2 * sizeof(unsigned int);
  hipMemsetAsync(d_ws, 0, zero_bytes, stream);
  k_acc<<<GRID_A, 256, 0, stream>>>(pred, inst, ws);
  k_hist<<<GRID_H, 256, 0, stream>>>(pred, inst, ws);
  k_lovasz<<<16, 256, 0, stream>>>(ws, out);
}

// Round 4
// 197.663 us; speedup vs baseline: 5.0843x; 1.0548x over previous
//
#include <hip/hip_runtime.h>
#include <math.h>

#define BB 2
#define KK 8
#define NPB (1<<20)       // pixels per batch item: T*H*W
#define NB 256            // histogram bins over error in [0,2]
#define HALF_NB_F 128.0f
#define NCOPY 64

#define PXB_H 1024
#define GRID_H (BB*NPB/PXB_H)   // 2048
#define ITERS_H (PXB_H/512)     // 2 (2 px/thread)
#define PXB_A 4096
#define GRID_A (BB*NPB/PXB_A)   // 512
#define ITERS_A (PXB_A/1024)    // 4 (4 px/thread)

#define STEP_T (0.1f/31.0f)
#define STEP_Y (1.6f/799.0f)
#define STEP_X (4.16f/1999.0f)

// ws float-offset layout
#define OFF_ACC 0       // 96: seg*6 + {count, s_sig, s_sig2, s_t, s_y, s_x}
#define OFF_SEEDBG 96
#define OFF_SEEDFG 98
#define OFF_PRM 100     // 96: seg*6 + {ct, cy, cx, s_exp, var_k, present}
#define OFF_INSTK 200   // 16
#define CNT0 240        // uint counter (k_acc last-block)
#define CNT1 241        // uint counter (k_lovasz last-block)
#define OFF_HIST_F 256  // NCOPY copies of [seg][bin] u64 (neg low32, pos high32)

// ---------------- pass 1: per-(b,k) sums + fused params ----------------
__global__ __launch_bounds__(256) void k_acc(const float* __restrict__ pred,
                                             const int* __restrict__ inst,
                                             float* __restrict__ ws) {
  __shared__ float s[48 * 256];
  __shared__ int lastA;
  int tid = threadIdx.x;
  for (int f = 0; f < 48; ++f) s[f * 256 + tid] = 0.f;
  __syncthreads();
  int blk = blockIdx.x;
  int b = blk >> 8;
  int rbase = (blk & 255) * PXB_A;
  const float* sig_p = pred + ((size_t)b * 5 << 20) + (3 << 20);
  const int* ip = inst + ((size_t)b << 20);
  for (int it = 0; it < ITERS_A; ++it) {
    int r = rbase + it * 1024 + 4 * tid;
    float4 sg = *(const float4*)(sig_p + r);
    int4 id4 = *(const int4*)(ip + r);
    int t = r >> 17, h = (r >> 9) & 255, w = r & 511;
    float sv[4] = {sg.x, sg.y, sg.z, sg.w};
    int iv[4] = {id4.x, id4.y, id4.z, id4.w};
    #pragma unroll
    for (int j = 0; j < 4; ++j) {
      if (iv[j] > 0) {
        int base = (iv[j] - 1) * 1536 + tid;
        s[base]        += 1.f;
        s[base + 256]  += sv[j];
        s[base + 512]  += sv[j] * sv[j];
        s[base + 768]  += (float)t;
        s[base + 1024] += (float)h;
        s[base + 1280] += (float)(w + j);
      }
    }
  }
  for (int lev = 7; lev >= 0; --lev) {
    int off = 1 << lev;
    __syncthreads();
    for (int idx = tid; idx < 48 * off; idx += 256) {
      int f = idx >> lev, c = idx & (off - 1);
      s[f * 256 + c] += s[f * 256 + c + off];
    }
  }
  __syncthreads();
  if (tid < 48) {
    float v = s[tid * 256];
    int j = tid % 6;
    if (j == 3) v *= STEP_T;
    else if (j == 4) v *= STEP_Y;
    else if (j == 5) v *= STEP_X;
    atomicAdd(&ws[OFF_ACC + b * 48 + tid], v);
  }
  __syncthreads();
  if (tid == 0) {
    __threadfence();
    lastA = (atomicAdd((unsigned*)ws + CNT0, 1u) == GRID_A - 1) ? 1 : 0;
  }
  __syncthreads();
  if (lastA && tid < 16) {
    __threadfence();
    float cnt = atomicAdd(&ws[OFF_ACC + tid*6 + 0], 0.f);
    float s1  = atomicAdd(&ws[OFF_ACC + tid*6 + 1], 0.f);
    float s2  = atomicAdd(&ws[OFF_ACC + tid*6 + 2], 0.f);
    float st  = atomicAdd(&ws[OFF_ACC + tid*6 + 3], 0.f);
    float sy  = atomicAdd(&ws[OFF_ACC + tid*6 + 4], 0.f);
    float sx  = atomicAdd(&ws[OFF_ACC + tid*6 + 5], 0.f);
    float safe = fmaxf(cnt, 1.f);
    float smean = s1 / safe;
    ws[OFF_PRM + tid*6 + 0] = st / safe;
    ws[OFF_PRM + tid*6 + 1] = sy / safe;
    ws[OFF_PRM + tid*6 + 2] = sx / safe;
    ws[OFF_PRM + tid*6 + 3] = __expf(10.f * smean);
    ws[OFF_PRM + tid*6 + 4] = s2 / safe - smean * smean;
    ws[OFF_PRM + tid*6 + 5] = (cnt > 0.f) ? 1.f : 0.f;
  }
}

__device__ __forceinline__ float fast_tanh(float x) {
  x = fminf(fmaxf(x, -15.f), 15.f);
  float ex = __expf(2.f * x);
  return (ex - 1.f) / (ex + 1.f);
}

// ---------------- pass 2: LDS-private histogram + seed losses ----------------
__global__ __launch_bounds__(256, 8) void k_hist(const float* __restrict__ pred,
                                                 const int* __restrict__ inst,
                                                 float* __restrict__ ws) {
  __shared__ unsigned int hist[KK * NB];  // packed: neg low16, pos high16
  __shared__ float Ps[KK * 4];
  __shared__ unsigned int pmask_s;
  __shared__ float wred[8];
  int tid = threadIdx.x;
  int blk = blockIdx.x;
  int b = blk >> 10;
  for (int i = tid; i < KK * NB; i += 256) hist[i] = 0u;
  if (tid < KK) {
    int seg = b * 8 + tid;
    Ps[tid*4+0] = ws[OFF_PRM + seg*6 + 0];
    Ps[tid*4+1] = ws[OFF_PRM + seg*6 + 1];
    Ps[tid*4+2] = ws[OFF_PRM + seg*6 + 2];
    Ps[tid*4+3] = ws[OFF_PRM + seg*6 + 3];
  }
  if (tid == 0) {
    unsigned m = 0;
    for (int k = 0; k < KK; ++k)
      if (ws[OFF_PRM + (b*8+k)*6 + 5] > 0.f) m |= 1u << k;
    pmask_s = m;
  }
  __syncthreads();
  float ct[KK], cy[KK], cx[KK], se[KK];
  #pragma unroll
  for (int k = 0; k < KK; ++k) {
    ct[k] = Ps[k*4+0]; cy[k] = Ps[k*4+1]; cx[k] = Ps[k*4+2]; se[k] = Ps[k*4+3];
  }
  unsigned pmask = pmask_s;
  int rbase = (blk & 1023) * PXB_H;
  const float* pb = pred + ((size_t)b * 5 << 20);
  const int* ip = inst + ((size_t)b << 20);
  float sbg = 0.f, sfg = 0.f;
  int lane = tid & 63;
  for (int it = 0; it < ITERS_H; ++it) {
    int r = rbase + it * 512 + 2 * tid;
    int t = r >> 17, h = (r >> 9) & 255, w = r & 511;
    float2 p0 = *(const float2*)(pb + r);
    float2 p1 = *(const float2*)(pb + (1 << 20) + r);
    float2 p2 = *(const float2*)(pb + (2 << 20) + r);
    float2 p4 = *(const float2*)(pb + (4 << 20) + r);
    int2 id2 = *(const int2*)(ip + r);
    float e0a = fast_tanh(p0.x) + t * STEP_T;
    float e0b = fast_tanh(p0.y) + t * STEP_T;
    float e1a = fast_tanh(p1.x) + h * STEP_Y;
    float e1b = fast_tanh(p1.y) + h * STEP_Y;
    float e2a = fast_tanh(p2.x) + w * STEP_X;
    float e2b = fast_tanh(p2.y) + (w + 1) * STEP_X;
    float seeda = 1.f / (1.f + __expf(-p4.x));
    float seedb = 1.f / (1.f + __expf(-p4.y));
    if (id2.x == 0) sbg += seeda * seeda;
    if (id2.y == 0) sbg += seedb * seedb;
    #pragma unroll
    for (int k = 0; k < KK; ++k) {
      if (!((pmask >> k) & 1)) continue;   // wave-uniform
      float dta = e0a - ct[k], dya = e1a - cy[k], dxa = e2a - cx[k];
      float dtb = e0b - ct[k], dyb = e1b - cy[k], dxb = e2b - cx[k];
      float da = __expf(-se[k] * (dta*dta + dya*dya + dxa*dxa));
      float db = __expf(-se[k] * (dtb*dtb + dyb*dyb + dxb*dxb));
      bool laba = (id2.x == k + 1), labb = (id2.y == k + 1);
      if (laba) { float df = seeda - da; sfg += df * df; }
      if (labb) { float df = seedb - db; sfg += df * df; }
      float ea = laba ? (2.f - 2.f * da) : (2.f * da);
      float eb = labb ? (2.f - 2.f * db) : (2.f * db);
      int bina = min((int)(ea * HALF_NB_F), NB - 1);
      int binb = min((int)(eb * HALF_NB_F), NB - 1);
      bool lowa = (bina == 0), topa = (bina == NB - 1);
      bool lowb = (binb == 0), topb = (binb == NB - 1);
      unsigned long long mla = __ballot(laba), mlo_a = __ballot(lowa), mto_a = __ballot(topa);
      unsigned long long mlb = __ballot(labb), mlo_b = __ballot(lowb), mto_b = __ballot(topb);
      if (lane == 0) {
        unsigned vlow = (unsigned)__popcll(mlo_a & ~mla) + (unsigned)__popcll(mlo_b & ~mlb)
                      + (((unsigned)__popcll(mlo_a & mla) + (unsigned)__popcll(mlo_b & mlb)) << 16);
        unsigned vtop = (unsigned)__popcll(mto_a & ~mla) + (unsigned)__popcll(mto_b & ~mlb)
                      + (((unsigned)__popcll(mto_a & mla) + (unsigned)__popcll(mto_b & mlb)) << 16);
        if (vlow) atomicAdd(&hist[k * NB], vlow);
        if (vtop) atomicAdd(&hist[k * NB + NB - 1], vtop);
      }
      if (!lowa && !topa) atomicAdd(&hist[k * NB + bina], laba ? 0x10000u : 1u);
      if (!lowb && !topb) atomicAdd(&hist[k * NB + binb], labb ? 0x10000u : 1u);
    }
  }
  for (int off = 32; off; off >>= 1) {
    sbg += __shfl_down(sbg, off);
    sfg += __shfl_down(sfg, off);
  }
  if (lane == 0) { wred[(tid >> 6) * 2] = sbg; wred[(tid >> 6) * 2 + 1] = sfg; }
  __syncthreads();
  if (tid == 0) {
    atomicAdd(&ws[OFF_SEEDBG + b], wred[0] + wred[2] + wred[4] + wred[6]);
    atomicAdd(&ws[OFF_SEEDFG + b], wred[1] + wred[3] + wred[5] + wred[7]);
  }
  __syncthreads();
  // flush nonzero words as packed u64 atomics into copy (blk & 63)
  unsigned long long* gh = (unsigned long long*)(ws + OFF_HIST_F);
  size_t cbase = (size_t)(blk & (NCOPY - 1)) * (16 * NB) + (size_t)b * (8 * NB);
  for (int i = tid; i < KK * NB; i += 256) {
    unsigned v = hist[i];
    if (v) {
      unsigned long long pk = (unsigned long long)(v & 0xFFFFu)
                            | ((unsigned long long)(v >> 16) << 32);
      atomicAdd(&gh[cbase + i], pk);
    }
  }
}

// ---------------- pass 3: Lovasz per segment (single-chunk wave scan) + final ----------------
__global__ __launch_bounds__(256) void k_lovasz(float* __restrict__ ws, float* __restrict__ out) {
  int seg = blockIdx.x;               // b*8+k
  int tid = threadIdx.x;
  int lane = tid & 63, wv = tid >> 6;
  __shared__ unsigned long long wtot[4];
  __shared__ double dred[4];
  __shared__ int lastL;
  float pres = ws[OFF_PRM + seg*6 + 5];
  double total = 0.0;
  if (pres != 0.f) {
    double gts = (double)ws[OFF_ACC + seg*6 + 0];
    const unsigned long long* gh = (const unsigned long long*)(ws + OFF_HIST_F);
    int bin = NB - 1 - tid;           // descending-error position
    unsigned long long v = 0;
    size_t off0 = (size_t)seg * NB + (size_t)bin;
    #pragma unroll 8
    for (int c = 0; c < NCOPY; ++c) v += gh[off0 + (size_t)c * (16 * NB)];
    unsigned long long orig = v;
    #pragma unroll
    for (int o = 1; o < 64; o <<= 1) {
      unsigned long long u = (unsigned long long)__shfl_up((long long)v, o, 64);
      if (lane >= o) v += u;
    }
    if (lane == 63) wtot[wv] = v;
    __syncthreads();
    unsigned long long add = 0;
    for (int j = 0; j < wv; ++j) add += wtot[j];
    v += add;
    double sum = 0.0;
    if (orig) {
      unsigned int ip = (unsigned)(v >> 32), in_ = (unsigned)v;
      unsigned int ppx = (unsigned)(orig >> 32), nnx = (unsigned)orig;
      double ep = (double)(ip - ppx), en = (double)(in_ - nnx);
      double js = 1.0 - (gts - ep) / (gts + en);
      double je = 1.0 - (gts - (double)ip) / (gts + (double)in_);
      sum = ((double)bin + 0.5) * (2.0 / NB) * (je - js);
    }
    for (int o = 32; o; o >>= 1) sum += __shfl_down(sum, o);
    if (lane == 0) dred[wv] = sum;
    __syncthreads();
    if (tid == 0) total = dred[0] + dred[1] + dred[2] + dred[3];
  }
  if (tid == 0) {
    atomicExch(&ws[OFF_INSTK + seg], (float)total);
    __threadfence();
    lastL = (atomicAdd((unsigned*)ws + CNT1, 1u) == 15) ? 1 : 0;
  }
  __syncthreads();
  if (lastL && tid == 0) {
    __threadfence();
    double tot = 0.0;
    for (int bb = 0; bb < BB; ++bb) {
      double il = 0.0, vl = 0.0, ob = 0.0;
      for (int k2 = 0; k2 < KK; ++k2) {
        int s2 = bb * 8 + k2;
        double pr = (double)ws[OFF_PRM + s2*6 + 5];
        il += (double)atomicAdd(&ws[OFF_INSTK + s2], 0.f) * pr;
        vl += (double)ws[OFF_PRM + s2*6 + 4] * pr;
        ob += pr;
      }
      double so = (ob > 1.0) ? ob : 1.0;
      double sl = ((double)ws[OFF_SEEDBG + bb] + (double)ws[OFF_SEEDFG + bb]) / (256.0 * 512.0);
      tot += il / so + 10.0 * vl / so + sl;
    }
    out[0] = (float)(tot / BB);
  }
}

extern "C" void kernel_launch(void* const* d_in, const int* in_sizes, int n_in,
                              void* d_out, int out_size, void* d_ws, size_t ws_size,
                              hipStream_t stream) {
  const float* pred = (const float*)d_in[0];
  const int* inst = (const int*)d_in[1];
  float* ws = (float*)d_ws;
  float* out = (float*)d_out;
  size_t zero_bytes = 1024 + (size_t)NCOPY * 16 * NB * sizeof(unsigned long long);
  hipMemsetAsync(d_ws, 0, zero_bytes, stream);
  k_acc<<<GRID_A, 256, 0, stream>>>(pred, inst, ws);
  k_hist<<<GRID_H, 256, 0, stream>>>(pred, inst, ws);
  k_lovasz<<<16, 256, 0, stream>>>(ws, out);
}

// Round 5
// 174.974 us; speedup vs baseline: 5.7435x; 1.1297x over previous
//
#include <hip/hip_runtime.h>
#include <math.h>

#define BB 2
#define KK 8
#define NPB (1<<20)       // pixels per batch item: T*H*W
#define NB 256            // histogram bins over error in [0,2]
#define HALF_NB_F 128.0f
#define FAR_CUT 5.5452f   // ln(256): s*sq above this => bin 0 (non-label)

#define PXB_H 2048
#define GRID_H (BB*NPB/PXB_H)   // 1024 (512 per b)
#define ITERS_H (PXB_H/512)     // 4 (2 px/thread)
#define PXB_A 4096
#define GRID_A (BB*NPB/PXB_A)   // 512
#define ITERS_A (PXB_A/1024)    // 4 (4 px/thread)

#define STEP_T (0.1f/31.0f)
#define STEP_Y (1.6f/799.0f)
#define STEP_X (4.16f/1999.0f)

// ws float-offset layout
#define OFF_ACC 0       // 96: seg*6 + {count, s_sig, s_sig2, s_t, s_y, s_x}
#define OFF_SEEDBG 96
#define OFF_SEEDFG 98
#define OFF_PRM 100     // 96: seg*6 + {ct, cy, cx, s_exp, var_k, present}
#define CNT0 240        // uint counter (k_acc last-block)
#define CNT1 241        // uint counter (k_lovasz last-block)
#define OFF_GH2 512     // u64 seg-hist: [seg][bin], 16*256*8B = 32 KB (float 512..8704)
#define OFF_HIST_F 9216 // partial hists: u32 [blk][k*NB+bin] (neg16|pos16), 1024*8KB = 8 MB

// ---------------- pass 1: per-(b,k) sums + fused params ----------------
__global__ __launch_bounds__(256) void k_acc(const float* __restrict__ pred,
                                             const int* __restrict__ inst,
                                             float* __restrict__ ws) {
  __shared__ float s[48 * 256];
  __shared__ int lastA;
  int tid = threadIdx.x;
  for (int f = 0; f < 48; ++f) s[f * 256 + tid] = 0.f;
  __syncthreads();
  int blk = blockIdx.x;
  int b = blk >> 8;
  int rbase = (blk & 255) * PXB_A;
  const float* sig_p = pred + ((size_t)b * 5 << 20) + (3 << 20);
  const int* ip = inst + ((size_t)b << 20);
  for (int it = 0; it < ITERS_A; ++it) {
    int r = rbase + it * 1024 + 4 * tid;
    float4 sg = *(const float4*)(sig_p + r);
    int4 id4 = *(const int4*)(ip + r);
    int t = r >> 17, h = (r >> 9) & 255, w = r & 511;
    float sv[4] = {sg.x, sg.y, sg.z, sg.w};
    int iv[4] = {id4.x, id4.y, id4.z, id4.w};
    #pragma unroll
    for (int j = 0; j < 4; ++j) {
      if (iv[j] > 0) {
        int base = (iv[j] - 1) * 1536 + tid;
        s[base]        += 1.f;
        s[base + 256]  += sv[j];
        s[base + 512]  += sv[j] * sv[j];
        s[base + 768]  += (float)t;
        s[base + 1024] += (float)h;
        s[base + 1280] += (float)(w + j);
      }
    }
  }
  for (int lev = 7; lev >= 0; --lev) {
    int off = 1 << lev;
    __syncthreads();
    for (int idx = tid; idx < 48 * off; idx += 256) {
      int f = idx >> lev, c = idx & (off - 1);
      s[f * 256 + c] += s[f * 256 + c + off];
    }
  }
  __syncthreads();
  if (tid < 48) {
    float v = s[tid * 256];
    int j = tid % 6;
    if (j == 3) v *= STEP_T;
    else if (j == 4) v *= STEP_Y;
    else if (j == 5) v *= STEP_X;
    atomicAdd(&ws[OFF_ACC + b * 48 + tid], v);
  }
  __syncthreads();
  if (tid == 0) {
    __threadfence();
    lastA = (atomicAdd((unsigned*)ws + CNT0, 1u) == GRID_A - 1) ? 1 : 0;
  }
  __syncthreads();
  if (lastA && tid < 16) {
    __threadfence();
    float cnt = atomicAdd(&ws[OFF_ACC + tid*6 + 0], 0.f);
    float s1  = atomicAdd(&ws[OFF_ACC + tid*6 + 1], 0.f);
    float s2  = atomicAdd(&ws[OFF_ACC + tid*6 + 2], 0.f);
    float st  = atomicAdd(&ws[OFF_ACC + tid*6 + 3], 0.f);
    float sy  = atomicAdd(&ws[OFF_ACC + tid*6 + 4], 0.f);
    float sx  = atomicAdd(&ws[OFF_ACC + tid*6 + 5], 0.f);
    float safe = fmaxf(cnt, 1.f);
    float smean = s1 / safe;
    ws[OFF_PRM + tid*6 + 0] = st / safe;
    ws[OFF_PRM + tid*6 + 1] = sy / safe;
    ws[OFF_PRM + tid*6 + 2] = sx / safe;
    ws[OFF_PRM + tid*6 + 3] = __expf(10.f * smean);
    ws[OFF_PRM + tid*6 + 4] = s2 / safe - smean * smean;
    ws[OFF_PRM + tid*6 + 5] = (cnt > 0.f) ? 1.f : 0.f;
  }
}

__device__ __forceinline__ float fast_tanh(float x) {
  x = fminf(fmaxf(x, -15.f), 15.f);
  float ex = __expf(2.f * x);
  return (ex - 1.f) / (ex + 1.f);
}

// ---------------- pass 2: LDS-private histogram, plain-store flush ----------------
__global__ __launch_bounds__(256, 8) void k_hist(const float* __restrict__ pred,
                                                 const int* __restrict__ inst,
                                                 float* __restrict__ ws) {
  __shared__ unsigned int hist[KK * NB];  // packed: neg low16, pos high16
  __shared__ float Ps[KK * 4];
  __shared__ unsigned int pmask_s;
  __shared__ float wred[8];
  int tid = threadIdx.x;
  int blk = blockIdx.x;
  int b = blk >> 9;
  for (int i = tid; i < KK * NB; i += 256) hist[i] = 0u;
  if (tid < KK) {
    int seg = b * 8 + tid;
    Ps[tid*4+0] = ws[OFF_PRM + seg*6 + 0];
    Ps[tid*4+1] = ws[OFF_PRM + seg*6 + 1];
    Ps[tid*4+2] = ws[OFF_PRM + seg*6 + 2];
    Ps[tid*4+3] = ws[OFF_PRM + seg*6 + 3];
  }
  if (tid == 0) {
    unsigned m = 0;
    for (int k = 0; k < KK; ++k)
      if (ws[OFF_PRM + (b*8+k)*6 + 5] > 0.f) m |= 1u << k;
    pmask_s = m;
  }
  __syncthreads();
  float ct[KK], cy[KK], cx[KK], se[KK];
  #pragma unroll
  for (int k = 0; k < KK; ++k) {
    ct[k] = Ps[k*4+0]; cy[k] = Ps[k*4+1]; cx[k] = Ps[k*4+2]; se[k] = Ps[k*4+3];
  }
  unsigned pmask = pmask_s;
  int rbase = (blk & 511) * PXB_H;
  const float* pb = pred + ((size_t)b * 5 << 20);
  const int* ip = inst + ((size_t)b << 20);
  float sbg = 0.f, sfg = 0.f;
  int lane = tid & 63;
  for (int it = 0; it < ITERS_H; ++it) {
    int r = rbase + it * 512 + 2 * tid;
    int t = r >> 17, h = (r >> 9) & 255, w = r & 511;
    float2 p0 = *(const float2*)(pb + r);
    float2 p1 = *(const float2*)(pb + (1 << 20) + r);
    float2 p2 = *(const float2*)(pb + (2 << 20) + r);
    float2 p4 = *(const float2*)(pb + (4 << 20) + r);
    int2 id2 = *(const int2*)(ip + r);
    float e0a = fast_tanh(p0.x) + t * STEP_T;
    float e0b = fast_tanh(p0.y) + t * STEP_T;
    float e1a = fast_tanh(p1.x) + h * STEP_Y;
    float e1b = fast_tanh(p1.y) + h * STEP_Y;
    float e2a = fast_tanh(p2.x) + w * STEP_X;
    float e2b = fast_tanh(p2.y) + (w + 1) * STEP_X;
    float seeda = 1.f / (1.f + __expf(-p4.x));
    float seedb = 1.f / (1.f + __expf(-p4.y));
    if (id2.x == 0) sbg += seeda * seeda;
    if (id2.y == 0) sbg += seedb * seedb;
    #pragma unroll
    for (int k = 0; k < KK; ++k) {
      if (!((pmask >> k) & 1)) continue;   // wave-uniform
      float dta = e0a - ct[k], dya = e1a - cy[k], dxa = e2a - cx[k];
      float dtb = e0b - ct[k], dyb = e1b - cy[k], dxb = e2b - cx[k];
      float ssqa = se[k] * (dta*dta + dya*dya + dxa*dxa);
      float ssqb = se[k] * (dtb*dtb + dyb*dyb + dxb*dxb);
      bool laba = (id2.x == k + 1), labb = (id2.y == k + 1);
      bool need = (ssqa < FAR_CUT) || (ssqb < FAR_CUT) || laba || labb;
      if (__any(need)) {
        float da = __expf(-ssqa);
        float db = __expf(-ssqb);
        if (laba) { float df = seeda - da; sfg += df * df; }
        if (labb) { float df = seedb - db; sfg += df * df; }
        float ea = laba ? (2.f - 2.f * da) : (2.f * da);
        float eb = labb ? (2.f - 2.f * db) : (2.f * db);
        int bina = min((int)(ea * HALF_NB_F), NB - 1);
        int binb = min((int)(eb * HALF_NB_F), NB - 1);
        bool lowa = (bina == 0), topa = (bina == NB - 1);
        bool lowb = (binb == 0), topb = (binb == NB - 1);
        unsigned long long mla = __ballot(laba), mlo_a = __ballot(lowa), mto_a = __ballot(topa);
        unsigned long long mlb = __ballot(labb), mlo_b = __ballot(lowb), mto_b = __ballot(topb);
        if (lane == 0) {
          unsigned vlow = (unsigned)__popcll(mlo_a & ~mla) + (unsigned)__popcll(mlo_b & ~mlb)
                        + (((unsigned)__popcll(mlo_a & mla) + (unsigned)__popcll(mlo_b & mlb)) << 16);
          unsigned vtop = (unsigned)__popcll(mto_a & ~mla) + (unsigned)__popcll(mto_b & ~mlb)
                        + (((unsigned)__popcll(mto_a & mla) + (unsigned)__popcll(mto_b & mlb)) << 16);
          if (vlow) atomicAdd(&hist[k * NB], vlow);
          if (vtop) atomicAdd(&hist[k * NB + NB - 1], vtop);
        }
        if (!lowa && !topa) atomicAdd(&hist[k * NB + bina], laba ? 0x10000u : 1u);
        if (!lowb && !topb) atomicAdd(&hist[k * NB + binb], labb ? 0x10000u : 1u);
      } else {
        // whole wave far & non-label: 2 px/lane * 64 lanes into bin 0 (neg)
        if (lane == 0) atomicAdd(&hist[k * NB], 128u);
      }
    }
  }
  for (int off = 32; off; off >>= 1) {
    sbg += __shfl_down(sbg, off);
    sfg += __shfl_down(sfg, off);
  }
  if (lane == 0) { wred[(tid >> 6) * 2] = sbg; wred[(tid >> 6) * 2 + 1] = sfg; }
  __syncthreads();
  if (tid == 0) {
    atomicAdd(&ws[OFF_SEEDBG + b], wred[0] + wred[2] + wred[4] + wred[6]);
    atomicAdd(&ws[OFF_SEEDFG + b], wred[1] + wred[3] + wred[5] + wred[7]);
  }
  __syncthreads();
  // plain coalesced flush of this block's private histogram
  unsigned int* gp = (unsigned int*)(ws + OFF_HIST_F) + (size_t)blk * (KK * NB);
  for (int i = tid; i < KK * NB; i += 256) gp[i] = hist[i];
}

// ---------------- pass 3: tree-reduce partials + Lovasz scan + final ----------------
__global__ __launch_bounds__(256) void k_lovasz(float* __restrict__ ws, float* __restrict__ out) {
  int blk = blockIdx.x;               // 256 blocks: seg = blk>>4, bin-range = blk&15
  int tid = threadIdx.x;
  int seg = blk >> 4, range = blk & 15;
  int b = seg >> 3, k = seg & 7;
  __shared__ unsigned long long sred[256];
  __shared__ int lastL;
  __shared__ double segtot[16];
  // phase 1: sum 512 partial histograms over this seg's 16-bin range
  {
    int bin_off = tid & 15;
    int pgrp = tid >> 4;              // 0..15, each sums 32 partials
    const unsigned int* gh = (const unsigned int*)(ws + OFF_HIST_F);
    size_t base = ((size_t)b * 512 + (size_t)pgrp * 32) * (KK * NB)
                + (size_t)k * NB + (size_t)range * 16 + bin_off;
    unsigned int neg = 0, pos = 0;
    #pragma unroll 4
    for (int j = 0; j < 32; ++j) {
      unsigned v = gh[base + (size_t)j * (KK * NB)];
      neg += v & 0xFFFFu; pos += v >> 16;
    }
    sred[tid] = ((unsigned long long)pos << 32) | neg;
  }
  __syncthreads();
  if (tid < 16) {
    unsigned long long a = 0;
    #pragma unroll
    for (int j = 0; j < 16; ++j) a += sred[tid + j * 16];
    if (a) atomicAdd((unsigned long long*)(ws + OFF_GH2) + seg * NB + range * 16 + tid, a);
  }
  __syncthreads();
  if (tid == 0) {
    __threadfence();
    lastL = (atomicAdd((unsigned*)ws + CNT1, 1u) == 255) ? 1 : 0;
  }
  __syncthreads();
  if (!lastL) return;
  if (tid == 0) __threadfence();
  __syncthreads();
  // phase 2 (single block): scan all 16 segments, 4 waves x 4 segs
  int lane = tid & 63, wv = tid >> 6;
  unsigned long long* gh2 = (unsigned long long*)(ws + OFF_GH2);
  for (int s = wv; s < 16; s += 4) {
    double total = 0.0;
    if (ws[OFF_PRM + s*6 + 5] != 0.f) {
      double gts = (double)ws[OFF_ACC + s*6 + 0];
      unsigned long long carry = 0;
      double sum = 0.0;
      for (int c = 0; c < NB / 64; ++c) {
        int pos_ = c * 64 + lane;     // descending-error position
        int bin = NB - 1 - pos_;
        unsigned long long v = atomicAdd(&gh2[s * NB + bin], 0ull);
        unsigned long long orig = v;
        #pragma unroll
        for (int o = 1; o < 64; o <<= 1) {
          unsigned long long u = (unsigned long long)__shfl_up((long long)v, o, 64);
          if (lane >= o) v += u;
        }
        v += carry;
        if (orig) {
          unsigned int ip = (unsigned)(v >> 32), in_ = (unsigned)v;
          unsigned int ppx = (unsigned)(orig >> 32), nnx = (unsigned)orig;
          double ep = (double)(ip - ppx), en = (double)(in_ - nnx);
          double js = 1.0 - (gts - ep) / (gts + en);
          double je = 1.0 - (gts - (double)ip) / (gts + (double)in_);
          sum += ((double)bin + 0.5) * (2.0 / NB) * (je - js);
        }
        carry = (unsigned long long)__shfl((long long)v, 63, 64);
      }
      for (int o = 32; o; o >>= 1) sum += __shfl_down(sum, o);
      total = sum;                    // lane 0 holds it
    }
    if (lane == 0) segtot[s] = total;
  }
  __syncthreads();
  if (tid == 0) {
    double tot = 0.0;
    for (int bb = 0; bb < BB; ++bb) {
      double il = 0.0, vl = 0.0, ob = 0.0;
      for (int k2 = 0; k2 < KK; ++k2) {
        int s2 = bb * 8 + k2;
        double pr = (double)ws[OFF_PRM + s2*6 + 5];
        il += segtot[s2] * pr;
        vl += (double)ws[OFF_PRM + s2*6 + 4] * pr;
        ob += pr;
      }
      double so = (ob > 1.0) ? ob : 1.0;
      double sl = ((double)ws[OFF_SEEDBG + bb] + (double)ws[OFF_SEEDFG + bb]) / (256.0 * 512.0);
      tot += il / so + 10.0 * vl / so + sl;
    }
    out[0] = (float)(tot / BB);
  }
}

extern "C" void kernel_launch(void* const* d_in, const int* in_sizes, int n_in,
                              void* d_out, int out_size, void* d_ws, size_t ws_size,
                              hipStream_t stream) {
  const float* pred = (const float*)d_in[0];
  const int* inst = (const int*)d_in[1];
  float* ws = (float*)d_ws;
  float* out = (float*)d_out;
  // zero: counters/ACC/seed (1 KB) + seg-hist (32 KB). Partial hists are fully
  // overwritten by k_hist's plain stores — no zeroing needed.
  hipMemsetAsync(d_ws, 0, (size_t)OFF_HIST_F * sizeof(float), stream);
  k_acc<<<GRID_A, 256, 0, stream>>>(pred, inst, ws);
  k_hist<<<GRID_H, 256, 0, stream>>>(pred, inst, ws);
  k_lovasz<<<256, 256, 0, stream>>>(ws, out);
}